// Round 1
// baseline (967.919 us; speedup 1.0000x reference)
//
#include <hip/hip_runtime.h>
#include <math.h>

#define TPB 256

__device__ __forceinline__ float gelu_erf(float x){
  return 0.5f * x * (1.0f + erff(x * 0.70710678118654752440f));
}

// ---------------- CSR build ----------------

__global__ __launch_bounds__(TPB) void deg_kernel(const int* __restrict__ dst, int* __restrict__ deg, int E){
  int i = blockIdx.x * TPB + threadIdx.x;
  if (i < E) atomicAdd(&deg[dst[i]], 1);
}

__global__ __launch_bounds__(TPB) void scan1(const int* __restrict__ in, int* __restrict__ out,
                                             int* __restrict__ bsums, int n){
  int gid = blockIdx.x * TPB + threadIdx.x;
  int v = (gid < n) ? in[gid] : 0;
  int lane = threadIdx.x & 63;
  int wid  = threadIdx.x >> 6;
  int x = v;
  #pragma unroll
  for (int off = 1; off < 64; off <<= 1){
    int y = __shfl_up(x, off);
    if (lane >= off) x += y;
  }
  __shared__ int wtot[TPB/64];
  __shared__ int woff[TPB/64];
  if (lane == 63) wtot[wid] = x;
  __syncthreads();
  if (threadIdx.x == 0){
    int s = 0;
    #pragma unroll
    for (int i = 0; i < TPB/64; ++i){ woff[i] = s; s += wtot[i]; }
    bsums[blockIdx.x] = s;
  }
  __syncthreads();
  if (gid < n) out[gid] = x - v + woff[wid];   // block-local exclusive scan
}

__global__ void scan2(int* __restrict__ bsums, int nb){
  if (threadIdx.x == 0 && blockIdx.x == 0){
    int s = 0;
    for (int i = 0; i < nb; ++i){ int t = bsums[i]; bsums[i] = s; s += t; }
  }
}

__global__ __launch_bounds__(TPB) void scan3(int* __restrict__ row_ptr, const int* __restrict__ boffs,
                                             int n, int E){
  int gid = blockIdx.x * TPB + threadIdx.x;
  if (gid < n) row_ptr[gid] += boffs[blockIdx.x];
  if (gid == 0) row_ptr[n] = E;
}

__global__ __launch_bounds__(TPB) void dinv_kernel(const int* __restrict__ deg, float* __restrict__ dinv, int n){
  int i = blockIdx.x * TPB + threadIdx.x;
  if (i < n) dinv[i] = rsqrtf((float)deg[i] + 2.0f);
}

__global__ __launch_bounds__(TPB) void fill_kernel(const int* __restrict__ src, const int* __restrict__ dst,
                                                   const int* __restrict__ row_ptr, int* __restrict__ cursor,
                                                   int* __restrict__ csr_src, int E){
  int i = blockIdx.x * TPB + threadIdx.x;
  if (i < E){
    int d = dst[i];
    int pos = atomicAdd(&cursor[d], 1);
    csr_src[row_ptr[d] + pos] = src[i];
  }
}

// ---------------- GEMM N x 128 @ 128 x 128 (fp32 vector) ----------------
// block: 256 threads, tile 64 rows x 128 cols, thread tile 4x8.

__global__ __launch_bounds__(TPB) void gemm128(const float* __restrict__ A, const float* __restrict__ W,
                                               float* __restrict__ C, int n){
  __shared__ float As[16][64];    // transposed A tile: As[k][r]
  __shared__ float Ws[16][128];
  int tid = threadIdx.x;
  int block_row = blockIdx.x * 64;

  int lr = tid >> 2;              // 0..63 (A-load row)
  int lk = (tid & 3) * 4;         // 0,4,8,12 (A-load k)
  int wk = tid >> 4;              // 0..15 (W-load k)
  int wc = (tid & 15) * 8;        // 0..120 (W-load col)
  int cw = (tid & 15) * 8;        // compute cols
  int rw = (tid >> 4) * 4;        // compute rows

  float acc[4][8];
  #pragma unroll
  for (int i = 0; i < 4; ++i)
    #pragma unroll
    for (int j = 0; j < 8; ++j) acc[i][j] = 0.f;

  for (int k0 = 0; k0 < 128; k0 += 16){
    float4 a = make_float4(0,0,0,0);
    int ar = block_row + lr;
    if (ar < n) a = *(const float4*)(A + (size_t)ar*128 + k0 + lk);
    float4 w0 = *(const float4*)(W + (size_t)(k0+wk)*128 + wc);
    float4 w1 = *(const float4*)(W + (size_t)(k0+wk)*128 + wc + 4);
    __syncthreads();
    As[lk+0][lr] = a.x; As[lk+1][lr] = a.y; As[lk+2][lr] = a.z; As[lk+3][lr] = a.w;
    *(float4*)&Ws[wk][wc]   = w0;
    *(float4*)&Ws[wk][wc+4] = w1;
    __syncthreads();
    #pragma unroll
    for (int k = 0; k < 16; ++k){
      float4 av = *(const float4*)&As[k][rw];
      float a4[4] = {av.x, av.y, av.z, av.w};
      float wv[8];
      *(float4*)&wv[0] = *(const float4*)&Ws[k][cw];
      *(float4*)&wv[4] = *(const float4*)&Ws[k][cw+4];
      #pragma unroll
      for (int i = 0; i < 4; ++i)
        #pragma unroll
        for (int j = 0; j < 8; ++j)
          acc[i][j] = fmaf(a4[i], wv[j], acc[i][j]);
    }
  }
  #pragma unroll
  for (int i = 0; i < 4; ++i){
    int r = block_row + rw + i;
    if (r < n){
      *(float4*)(C + (size_t)r*128 + cw)     = make_float4(acc[i][0],acc[i][1],acc[i][2],acc[i][3]);
      *(float4*)(C + (size_t)r*128 + cw + 4) = make_float4(acc[i][4],acc[i][5],acc[i][6],acc[i][7]);
    }
  }
}

// ---------------- GEMM N x 128 @ 128 x 40 (+bias) ----------------
// block: 256 threads, tile 128 rows x 40 cols, thread tile 4x5.

__global__ __launch_bounds__(TPB) void gemm40(const float* __restrict__ A, const float* __restrict__ W,
                                              const float* __restrict__ bias, float* __restrict__ C, int n){
  __shared__ float Ws[128][40];
  __shared__ float As[16][128];
  __shared__ float bs[40];
  int tid = threadIdx.x;
  for (int i = tid; i < 128*40; i += TPB) (&Ws[0][0])[i] = W[i];
  if (tid < 40) bs[tid] = bias[tid];

  int block_row = blockIdx.x * 128;
  int cg = (tid & 7) * 5;     // cols
  int rg = (tid >> 3) * 4;    // rows
  int lr = tid >> 1;          // A-load row 0..127
  int lk = (tid & 1) * 8;     // A-load k 0/8

  float acc[4][5];
  #pragma unroll
  for (int i = 0; i < 4; ++i)
    #pragma unroll
    for (int j = 0; j < 5; ++j) acc[i][j] = 0.f;

  for (int k0 = 0; k0 < 128; k0 += 16){
    float4 a0 = make_float4(0,0,0,0), a1 = a0;
    int ar = block_row + lr;
    if (ar < n){
      a0 = *(const float4*)(A + (size_t)ar*128 + k0 + lk);
      a1 = *(const float4*)(A + (size_t)ar*128 + k0 + lk + 4);
    }
    __syncthreads();
    As[lk+0][lr]=a0.x; As[lk+1][lr]=a0.y; As[lk+2][lr]=a0.z; As[lk+3][lr]=a0.w;
    As[lk+4][lr]=a1.x; As[lk+5][lr]=a1.y; As[lk+6][lr]=a1.z; As[lk+7][lr]=a1.w;
    __syncthreads();
    #pragma unroll
    for (int k = 0; k < 16; ++k){
      float4 av = *(const float4*)&As[k][rg];
      float a4[4] = {av.x, av.y, av.z, av.w};
      #pragma unroll
      for (int j = 0; j < 5; ++j){
        float w = Ws[k0+k][cg+j];
        #pragma unroll
        for (int i = 0; i < 4; ++i) acc[i][j] = fmaf(a4[i], w, acc[i][j]);
      }
    }
  }
  #pragma unroll
  for (int i = 0; i < 4; ++i){
    int r = block_row + rg + i;
    if (r < n){
      #pragma unroll
      for (int j = 0; j < 5; ++j) C[(size_t)r*40 + cg + j] = acc[i][j] + bs[cg+j];
    }
  }
}

// ---------------- Aggregation: 32 lanes per dst node, float4/lane ----------------
// MODE 0: out = gelu(agg + self + bias)
// MODE 1: out = gelu(agg + self + bias + res)
// MODE 2: out = agg + self                       (pure linear Agg)

template<int MODE>
__global__ __launch_bounds__(TPB) void agg128(const float4* __restrict__ xw4, const float4* __restrict__ res4,
                                              const float* __restrict__ dinv, const int* __restrict__ row_ptr,
                                              const int* __restrict__ csr_src, const float4* __restrict__ bias4,
                                              float4* __restrict__ out4, int n){
  int g = (int)((blockIdx.x * (unsigned)TPB + threadIdx.x) >> 5);
  if (g >= n) return;
  int lane = threadIdx.x & 31;
  float di = dinv[g];
  int beg = row_ptr[g], end = row_ptr[g+1];
  float ax = 0.f, ay = 0.f, az = 0.f, aw = 0.f;
  for (int base = beg; base < end; base += 32){
    int m = end - base; if (m > 32) m = 32;
    int   sl = (lane < m) ? csr_src[base + lane] : 0;
    float cl = (lane < m) ? dinv[sl] * di : 0.f;
    for (int j = 0; j < m; ++j){
      int   s = __shfl(sl, j, 32);
      float c = __shfl(cl, j, 32);
      float4 v = xw4[(size_t)s * 32 + lane];
      ax = fmaf(c, v.x, ax);
      ay = fmaf(c, v.y, ay);
      az = fmaf(c, v.z, az);
      aw = fmaf(c, v.w, aw);
    }
  }
  float4 sv = xw4[(size_t)g * 32 + lane];
  float sc = 2.0f * di * di;
  ax = fmaf(sc, sv.x, ax); ay = fmaf(sc, sv.y, ay);
  az = fmaf(sc, sv.z, az); aw = fmaf(sc, sv.w, aw);
  if (MODE != 2){
    float4 bb = bias4[lane];
    ax += bb.x; ay += bb.y; az += bb.z; aw += bb.w;
  }
  if (MODE == 1){
    float4 rv = res4[(size_t)g * 32 + lane];
    ax += rv.x; ay += rv.y; az += rv.z; aw += rv.w;
  }
  if (MODE != 2){
    ax = gelu_erf(ax); ay = gelu_erf(ay); az = gelu_erf(az); aw = gelu_erf(aw);
  }
  out4[(size_t)g * 32 + lane] = make_float4(ax, ay, az, aw);
}

// ---------------- launch ----------------

extern "C" void kernel_launch(void* const* d_in, const int* in_sizes, int n_in,
                              void* d_out, int out_size, void* d_ws, size_t ws_size,
                              hipStream_t stream){
  const float* x  = (const float*)d_in[0];
  const int*   ei = (const int*)d_in[1];
  const float* W0 = (const float*)d_in[2];
  const float* b0 = (const float*)d_in[3];
  const float* W1 = (const float*)d_in[4];
  const float* b1 = (const float*)d_in[5];
  const float* W2 = (const float*)d_in[6];
  const float* b2 = (const float*)d_in[7];
  const float* W3 = (const float*)d_in[8];
  const float* b3 = (const float*)d_in[9];
  float* out = (float*)d_out;

  const int N = in_sizes[0] / 128;
  const int E = in_sizes[1] / 2;
  const int* src = ei;
  const int* dst = ei + E;

  char* ws = (char*)d_ws;
  size_t off = 0;
  auto alloc = [&](size_t bytes) -> void* {
    void* p = ws + off;
    off += (bytes + 255) & ~(size_t)255;
    return p;
  };
  float* xw    = (float*)alloc((size_t)N * 128 * 4);
  float* gA    = (float*)alloc((size_t)N * 128 * 4);
  float* gB    = (float*)alloc((size_t)N * 128 * 4);
  int* csr     = (int*)  alloc((size_t)E * 4);
  int* row_ptr = (int*)  alloc((size_t)(N + 1) * 4);
  int* deg     = (int*)  alloc((size_t)N * 4);
  int* cursor  = (int*)  alloc((size_t)N * 4);
  float* dnv   = (float*)alloc((size_t)N * 4);
  int nb = (N + TPB - 1) / TPB;
  int* bsums   = (int*)  alloc((size_t)nb * 4);
  (void)ws_size; (void)n_in; (void)out_size;

  hipMemsetAsync(deg,    0, (size_t)N * 4, stream);
  hipMemsetAsync(cursor, 0, (size_t)N * 4, stream);

  int ebl = (E + TPB - 1) / TPB;
  deg_kernel<<<ebl, TPB, 0, stream>>>(dst, deg, E);
  scan1<<<nb, TPB, 0, stream>>>(deg, row_ptr, bsums, N);
  scan2<<<1, 64, 0, stream>>>(bsums, nb);
  scan3<<<nb, TPB, 0, stream>>>(row_ptr, bsums, N, E);
  dinv_kernel<<<nb, TPB, 0, stream>>>(deg, dnv, N);
  fill_kernel<<<ebl, TPB, 0, stream>>>(src, dst, row_ptr, cursor, csr, E);

  int gblocks = (N + 63) / 64;
  int ablocks = (N * 32 + TPB - 1) / TPB;
  int g40     = (N + 127) / 128;

  // L0: g = gelu(conv(x))
  gemm128<<<gblocks, TPB, 0, stream>>>(x, W0, xw, N);
  agg128<0><<<ablocks, TPB, 0, stream>>>((const float4*)xw, nullptr, dnv, row_ptr, csr,
                                         (const float4*)b0, (float4*)gA, N);
  // L1: g = gelu(g + conv(g))
  gemm128<<<gblocks, TPB, 0, stream>>>(gA, W1, xw, N);
  agg128<1><<<ablocks, TPB, 0, stream>>>((const float4*)xw, (const float4*)gA, dnv, row_ptr, csr,
                                         (const float4*)b1, (float4*)gB, N);
  // L2: g = gelu(g + conv(g))
  gemm128<<<gblocks, TPB, 0, stream>>>(gB, W2, xw, N);
  agg128<1><<<ablocks, TPB, 0, stream>>>((const float4*)xw, (const float4*)gB, dnv, row_ptr, csr,
                                         (const float4*)b2, (float4*)gA, N);
  // L3: out = Agg(g) @ W3 + b3   (Agg commutes with right-multiplication)
  agg128<2><<<ablocks, TPB, 0, stream>>>((const float4*)gA, nullptr, dnv, row_ptr, csr,
                                         nullptr, (float4*)xw, N);
  gemm40<<<g40, TPB, 0, stream>>>(xw, W3, b3, out, N);
}